// Round 6
// baseline (88.628 us; speedup 1.0000x reference)
//
#include <hip/hip_runtime.h>

#define CAM_FL 540.0f
#define CAM_W  640
#define CAM_H  480
#define RADIUS 2
#define KSIZE  (2 * RADIUS + 1)   // 5
#define TAPS   (KSIZE * KSIZE)    // 25
#define BLK    256

typedef float floatx4 __attribute__((ext_vector_type(4)));  // native vec for nontemporal builtin

// Single kernel: coalesced LDS stage of locs -> project -> block-local
// compaction (separable-Gaussian precompute) -> 2-deep-pipelined tap splat.
// R2 lesson: no global counters (same-address global atomics ~28 cyc/op).
// R4 lesson: splat is latency-bound, not exp-issue-bound -> this round
// targets the three exposed-latency chains (locs split loads, serial depth
// gathers, cross-XCD depth traffic).
__global__ __launch_bounds__(BLK) void particle_project_kernel(
    const float* __restrict__ locs,        // [B, N, 3]
    const float* __restrict__ camera_pose, // [B, 3]
    const float* __restrict__ camera_rot,  // [B, 4]
    const float* __restrict__ depth,       // [B, H, W]
    float* __restrict__ out,               // [B, H, W]
    int N, int chunks, int swiz)
{
#pragma clang fp contract(off)
    __shared__ float s_loc[BLK * 3];
    __shared__ int   s_iy0[BLK];
    __shared__ int   s_jx0[BLK];
    __shared__ float s_z[BLK];
    __shared__ float s_wy[BLK][KSIZE];   // stride 5: gcd(5,32)=1 -> conflict-free
    __shared__ float s_wx[BLK][KSIZE];
    __shared__ int   s_cnt;

    const int tid = threadIdx.x;
    const int bid = blockIdx.x;

    // XCD-aware swizzle: linear block id i goes to XCD i%8 (round-robin), so
    // mapping batch b to ids with i%8 in {2b,2b+1} pins each batch's depth
    // slice (1.23 MB) into 2 XCDs' L2. Pure function of blockIdx -> safe.
    int b, chunk;
    if (swiz) { b = (bid & 7) >> 1; chunk = ((bid >> 3) << 1) | (bid & 1); }
    else      { b = bid / chunks;   chunk = bid - b * chunks; }

    const int n0   = chunk * BLK;
    const int nrem = min(BLK, N - n0);

    if (tid == 0) s_cnt = 0;

    // --- coalesced nontemporal float4 stage of this block's locs into LDS ---
    {
        const float* src = locs + ((size_t)b * N + (size_t)n0) * 3;
        const int remf = nrem * 3;
        const int nv4  = remf >> 2;
        const floatx4* src4 = (const floatx4*)src;   // 16B-aligned: (b*N+n0)*3*4 % 16 == 0 for N,BLK mult of 4
        for (int i = tid; i < nv4; i += BLK) {
            const floatx4 v = __builtin_nontemporal_load(src4 + i);
            s_loc[i * 4 + 0] = v.x; s_loc[i * 4 + 1] = v.y;
            s_loc[i * 4 + 2] = v.z; s_loc[i * 4 + 3] = v.w;
        }
        for (int i = (nv4 << 2) + tid; i < remf; i += BLK)
            s_loc[i] = src[i];
    }

    // --- camera params (uniform within block -> scalarized) ---
    const float qx_raw = camera_rot[b * 4 + 0];
    const float qy_raw = camera_rot[b * 4 + 1];
    const float qz_raw = camera_rot[b * 4 + 2];
    const float qw_raw = camera_rot[b * 4 + 3];
    const float norm2 = ((qx_raw * qx_raw + qy_raw * qy_raw) + qz_raw * qz_raw) + qw_raw * qw_raw;
    const float s = sqrtf(norm2);
    const float qx = -(qx_raw / s);
    const float qy = -(qy_raw / s);
    const float qz = -(qz_raw / s);
    const float qw =  (qw_raw / s);

    const float qx2 = qx * qx, qy2 = qy * qy, qz2 = qz * qz;
    const float qxqy = qx * qy, qxqz = qx * qz, qxqw = qx * qw;
    const float qyqz = qy * qz, qyqw = qy * qw, qzqw = qz * qw;
    const float r00 = (1.0f - 2.0f * qy2) - 2.0f * qz2;
    const float r10 = 2.0f * qxqy - 2.0f * qzqw;
    const float r20 = 2.0f * qxqz + 2.0f * qyqw;
    const float r01 = 2.0f * qxqy + 2.0f * qzqw;
    const float r11 = (1.0f - 2.0f * qx2) - 2.0f * qz2;
    const float r21 = 2.0f * qyqz - 2.0f * qxqw;
    const float r02 = 2.0f * qxqz - 2.0f * qyqw;
    const float r12 = 2.0f * qyqz + 2.0f * qxqw;
    const float r22 = (1.0f - 2.0f * qx2) - 2.0f * qy2;

    const float cpx = camera_pose[b * 3 + 0];
    const float cpy = camera_pose[b * 3 + 1];
    const float cpz = camera_pose[b * 3 + 2];

    __syncthreads();   // s_loc + s_cnt visible

    // --- projection from LDS (stride-3 read: 2-way bank alias = free) ---
    bool alive = (tid < nrem);
    float px = 0.0f, py = 0.0f, z = 0.0f;
    if (alive) {
        const float p0 = s_loc[tid * 3 + 0] - cpx;
        const float p1 = s_loc[tid * 3 + 1] - cpy;
        const float p2 = s_loc[tid * 3 + 2] - cpz;

        // p' = p . R, association order matches reference ((a+b)+c)
        const float x = (p0 * r00 + p1 * r10) + p2 * r20;
        const float y = (p0 * r01 + p1 * r11) + p2 * r21;
        z             = (p0 * r02 + p1 * r12) + p2 * r22;

        alive = (z > 0.0f);
        if (alive) {
            px = (x / z) * CAM_FL + (float)CAM_W * 0.5f;
            py = (y / z) * CAM_FL + (float)CAM_H * 0.5f;
            // float-domain frustum cull before any int conversion
            alive = (px >= -(float)RADIUS && px < (float)(CAM_W + RADIUS) &&
                     py >= -(float)RADIUS && py < (float)(CAM_H + RADIUS));
        }
    }

    // --- block-local compaction: ballot + rank + one LDS atomic per wave ---
    const unsigned long long mask = __ballot(alive);
    const int lane   = tid & 63;
    const int rank   = __popcll(mask & ((1ull << lane) - 1ull));
    const int wcount = __popcll(mask);

    int wbase_v = 0;
    if (lane == 0 && wcount > 0) wbase_v = atomicAdd(&s_cnt, wcount);
    const int wbase = __shfl(wbase_v, 0);

    if (alive) {
        const int i   = wbase + rank;
        const int iy0 = (int)floorf(py);
        const int jx0 = (int)floorf(px);
        s_iy0[i] = iy0;
        s_jx0[i] = jx0;
        s_z[i]   = z;
        // separable Gaussian: 5 row + 5 col weights per survivor
#pragma unroll
        for (int k = 0; k < KSIZE; ++k) {
            const float dyf = (float)(iy0 + k - RADIUS) - py;
            const float dxf = (float)(jx0 + k - RADIUS) - px;
            s_wy[i][k] = __expf(-(dyf * dyf) * 0.5f);
            s_wx[i][k] = __expf(-(dxf * dxf) * 0.5f);
        }
    }

    __syncthreads();

    // --- tap-parallel splat, 2-deep software pipeline (both depth gathers
    //     issue before either result is consumed) ---
    const int ns    = s_cnt;
    const int total = ns * TAPS;
    const float* depth_b = depth + (size_t)b * (CAM_H * CAM_W);
    float*       out_b   = out   + (size_t)b * (CAM_H * CAM_W);

    for (int t0 = tid; t0 < total; t0 += 2 * BLK) {
        int   pixA[2];
        float zA[2], wA[2], dA[2];
        bool  okA[2];
#pragma unroll
        for (int u = 0; u < 2; ++u) {
            const int t = t0 + u * BLK;
            bool ok = (t < total);
            int si = 0, tap = 0;
            if (ok) { si = t / TAPS; tap = t - si * TAPS; }
            const int ti = tap / KSIZE;
            const int tj = tap - ti * KSIZE;
            const int iy = s_iy0[si] + ti - RADIUS;
            const int jx = s_jx0[si] + tj - RADIUS;
            ok = ok && ((unsigned)iy < (unsigned)CAM_H) && ((unsigned)jx < (unsigned)CAM_W);
            pixA[u] = iy * CAM_W + jx;
            zA[u]   = s_z[si];
            wA[u]   = s_wy[si][ti] * s_wx[si][tj];
            okA[u]  = ok;
            dA[u]   = 0.0f;
        }
#pragma unroll
        for (int u = 0; u < 2; ++u)
            if (okA[u]) dA[u] = depth_b[pixA[u]];
#pragma unroll
        for (int u = 0; u < 2; ++u)
            if (okA[u] && zA[u] <= dA[u]) atomicAdd(&out_b[pixA[u]], wA[u]);
    }
}

extern "C" void kernel_launch(void* const* d_in, const int* in_sizes, int n_in,
                              void* d_out, int out_size, void* d_ws, size_t ws_size,
                              hipStream_t stream) {
    const float* locs        = (const float*)d_in[0];
    const float* camera_pose = (const float*)d_in[1];
    const float* camera_rot  = (const float*)d_in[2];
    const float* depth_mask  = (const float*)d_in[3];
    float* out = (float*)d_out;

    const int B = in_sizes[1] / 3;             // camera_pose is [B,3]
    const int N = in_sizes[0] / (3 * B);       // locs is [B,N,3]
    const int chunks = (N + BLK - 1) / BLK;
    const int swiz = (B == 4 && (chunks % 2) == 0) ? 1 : 0;

    // harness poisons d_out with 0xAA before every timed launch
    (void)hipMemsetAsync(d_out, 0, (size_t)out_size * sizeof(float), stream);

    dim3 block(BLK, 1, 1);
    dim3 grid(B * chunks, 1, 1);
    particle_project_kernel<<<grid, block, 0, stream>>>(
        locs, camera_pose, camera_rot, depth_mask, out, N, chunks, swiz);
}